// Round 1
// baseline (438.301 us; speedup 1.0000x reference)
//
#include <hip/hip_runtime.h>

// 4 x f16 MFMA operand / 4 x f32 accumulator fragments
typedef _Float16 f16x4 __attribute__((ext_vector_type(4)));
typedef float    f32x4 __attribute__((ext_vector_type(4)));

// Legacy-shape MFMA: unambiguous, CDNA1+-documented lane layouts.
//   A: lane l holds A[m=l&15][k=4*(l>>4)+e]  (e=0..3)
//   B: lane l holds B[k=4*(l>>4)+e][n=l&15]
//   D: lane l, reg j holds D[4*(l>>4)+j][l&15]
#define MFMA16(A, B, C) __builtin_amdgcn_mfma_f32_16x16x16f16((A), (B), (C), 0, 0, 0)

// ushort-granular index into a [64][64] f16 LDS tile, XOR-swizzled so the
// 128B row stride doesn't collapse onto one bank group (T2-style, m201).
// XOR operates on bits >= 3 (units of 8 f16 = 16B), so 4-element (8B)
// vector accesses at col%4==0 stay contiguous and 8B-aligned.
__device__ __forceinline__ int sidx(int row, int col) {
  return (row << 6) + (col ^ ((row & 7) << 3));
}

__global__ __launch_bounds__(64, 2)
void BatchedBjorckOrthogonalization_45122926411979_kernel(const float* __restrict__ W,
                                                          float* __restrict__ OUT) {
  // One wave per 64x64 matrix; 13 Bjorck iterations fully on-chip.
  //   S1: T = w^T w   = WT . WT^T   (rowfrags of WT serve as both A and B)
  //   S2: P = w  T    = WB . TB^T   (T symmetric -> rowfrag(TB) is a valid B)
  //   w  = 1.5 w - 0.5 P            (fp32 master copy lives in registers)
  __shared__ _Float16 WB[4096];  // w    row-major, f16
  __shared__ _Float16 WT[4096];  // w^T  row-major, f16
  __shared__ _Float16 TB[4096];  // T = w^T w (symmetric), f16

  const int cl = (int)(threadIdx.x & 15);  // column / m-index within a 16x16 tile
  const int g  = (int)(threadIdx.x >> 4);  // k-group / row-quad index

  const size_t base = (size_t)blockIdx.x * 4096;
  const float* __restrict__ gw = W + base;
  float* __restrict__ go = OUT + base;

  f32x4 wreg[4][4];  // fp32 master copy of w in C/D layout:
                     // wreg[r][c][j] = w[16r + 4g + j][16c + cl]

  // ---------------- init: load fp32 w, seed WB and WT (one-time) ----------------
  #pragma unroll
  for (int r = 0; r < 4; ++r) {
    #pragma unroll
    for (int c = 0; c < 4; ++c) {
      #pragma unroll
      for (int j = 0; j < 4; ++j)
        wreg[r][c][j] = gw[(16 * r + 4 * g + j) * 64 + 16 * c + cl];
      f16x4 p;
      #pragma unroll
      for (int j = 0; j < 4; ++j) p[j] = (_Float16)wreg[r][c][j];
      // transposed write is the vector-friendly direction (4 consecutive rows/lane)
      *(f16x4*)(WT + sidx(16 * c + cl, 16 * r + 4 * g)) = p;
      #pragma unroll
      for (int j = 0; j < 4; ++j)
        WB[sidx(16 * r + 4 * g + j, 16 * c + cl)] = p[j];
    }
  }

  #pragma unroll 1
  for (int it = 0; it < 13; ++it) {
    // ---------------- S1: T = WT . WT^T = w^T w ----------------
    f32x4 acc[4][4];
    #pragma unroll
    for (int r = 0; r < 4; ++r)
      #pragma unroll
      for (int c = 0; c < 4; ++c)
        acc[r][c] = f32x4{0.f, 0.f, 0.f, 0.f};

    #pragma unroll
    for (int ks = 0; ks < 4; ++ks) {
      f16x4 F[4];
      #pragma unroll
      for (int t = 0; t < 4; ++t)
        F[t] = *(const f16x4*)(WT + sidx(16 * t + cl, 16 * ks + 4 * g));
      #pragma unroll
      for (int r = 0; r < 4; ++r)
        #pragma unroll
        for (int c = 0; c < 4; ++c)
          acc[r][c] = MFMA16(F[r], F[c], acc[r][c]);  // X . X^T tile (r,c)
    }

    // write T (symmetric): transposed vector write == T itself
    #pragma unroll
    for (int r = 0; r < 4; ++r) {
      #pragma unroll
      for (int c = 0; c < 4; ++c) {
        f16x4 p;
        #pragma unroll
        for (int j = 0; j < 4; ++j) p[j] = (_Float16)acc[r][c][j];
        *(f16x4*)(TB + sidx(16 * c + cl, 16 * r + 4 * g)) = p;
      }
    }

    // ---------------- S2: P = WB . TB^T = w . T ----------------
    #pragma unroll
    for (int r = 0; r < 4; ++r)
      #pragma unroll
      for (int c = 0; c < 4; ++c)
        acc[r][c] = f32x4{0.f, 0.f, 0.f, 0.f};

    #pragma unroll
    for (int ks = 0; ks < 4; ++ks) {
      f16x4 Af[4], Bf[4];
      #pragma unroll
      for (int r = 0; r < 4; ++r)
        Af[r] = *(const f16x4*)(WB + sidx(16 * r + cl, 16 * ks + 4 * g));
      #pragma unroll
      for (int c = 0; c < 4; ++c)
        Bf[c] = *(const f16x4*)(TB + sidx(16 * c + cl, 16 * ks + 4 * g));
      #pragma unroll
      for (int r = 0; r < 4; ++r)
        #pragma unroll
        for (int c = 0; c < 4; ++c)
          acc[r][c] = MFMA16(Af[r], Bf[c], acc[r][c]);
    }

    // ---------------- epilogue: w = 1.5 w - 0.5 P; refresh WB, WT ----------------
    #pragma unroll
    for (int r = 0; r < 4; ++r) {
      #pragma unroll
      for (int c = 0; c < 4; ++c) {
        wreg[r][c] = 1.5f * wreg[r][c] - 0.5f * acc[r][c];
        f16x4 p;
        #pragma unroll
        for (int j = 0; j < 4; ++j) p[j] = (_Float16)wreg[r][c][j];
        *(f16x4*)(WT + sidx(16 * c + cl, 16 * r + 4 * g)) = p;  // vector (transposed dir)
        #pragma unroll
        for (int j = 0; j < 4; ++j)
          WB[sidx(16 * r + 4 * g + j, 16 * c + cl)] = p[j];     // scalar (row-major dir)
      }
    }
  }

  // ---------------- final store (fp32) ----------------
  #pragma unroll
  for (int r = 0; r < 4; ++r)
    #pragma unroll
    for (int c = 0; c < 4; ++c)
      #pragma unroll
      for (int j = 0; j < 4; ++j)
        go[(16 * r + 4 * g + j) * 64 + 16 * c + cl] = wreg[r][c][j];
}

extern "C" void kernel_launch(void* const* d_in, const int* in_sizes, int n_in,
                              void* d_out, int out_size, void* d_ws, size_t ws_size,
                              hipStream_t stream) {
  (void)n_in; (void)d_ws; (void)ws_size; (void)out_size;
  const float* W = (const float*)d_in[0];
  float* out = (float*)d_out;
  const int batch = in_sizes[0] / 4096;  // 8192 matrices of 64x64
  BatchedBjorckOrthogonalization_45122926411979_kernel<<<dim3(batch), dim3(64), 0, stream>>>(W, out);
}

// Round 4
// 305.934 us; speedup vs baseline: 1.4327x; 1.4327x over previous
//
#include <hip/hip_runtime.h>

typedef _Float16 f16x4 __attribute__((ext_vector_type(4)));
typedef float    f32x4 __attribute__((ext_vector_type(4)));

// Legacy-shape MFMA (HW-verified by round 1):
//   A-frag: lane l elem e -> A[m = l&15][k = 4*(l>>4)+e]
//   B-frag: lane l elem e -> B[k = 4*(l>>4)+e][n = l&15]
//   D-frag: lane l reg  j -> D[row = 4*(l>>4)+j][col = l&15]
// Corollaries:
//   regs in D-layout of N, used as A  ==>  tile N^T
//   regs in D-layout of N, used as B  ==>  tile N
//   regs in A-layout of N, used as B  ==>  tile N^T
#define MFMA16(A, B, C) __builtin_amdgcn_mfma_f32_16x16x16f16((A), (B), (C), 0, 0, 0)

// dword-granular swizzled index into a [64][64] f32 LDS tile.
// XOR col bits 4-5 with (row>>2)&3 — float4 groups stay intact, and the
// D-pattern column-strip accesses (4 rows x 16 cols) land 2-way/free.
__device__ __forceinline__ int sw32(int row, int col) {
  return (row << 6) + (col ^ (((row >> 2) & 3) << 4));
}

__global__ __launch_bounds__(64, 2)
void BatchedBjorckOrthogonalization_45122926411979_kernel(const float* __restrict__ W,
                                                          float* __restrict__ OUT) {
  // One wave per 64x64 matrix. Master Z kept in fp32 D-layout across all 13
  // iterations (no orientation alternation):
  //   G   = Z^T Z                  (self-product of D-frags: correct-side Gram)
  //   ZhT = Z-as-A-frags           (identity-MFMA transpose, no LDS)
  //   Z'  = 1.5 Z + Z.(-0.5 G)     (linear term in fp32; output lands in D-layout)
  __shared__ float L[4096];

  const int tid = (int)threadIdx.x;
  const int cl = tid & 15;   // column within a 16-wide tile
  const int g  = tid >> 4;   // row-quad / k-group
  const size_t base = (size_t)blockIdx.x * 4096;

  // ---- stage w through LDS (vectorized global loads, swizzled) ----
  #pragma unroll
  for (int i = 0; i < 16; ++i) {
    const int row = 4 * i + g;
    f32x4 v = *(const f32x4*)(W + base + row * 64 + 4 * cl);
    *(f32x4*)(L + sw32(row, 4 * cl)) = v;
  }

  // ---- fp32 master in D-layout: R[i][j][e] = w[16i+4g+e][16j+cl] ----
  f32x4 R[4][4];
  #pragma unroll
  for (int i = 0; i < 4; ++i)
    #pragma unroll
    for (int j = 0; j < 4; ++j)
      #pragma unroll
      for (int e = 0; e < 4; ++e)
        R[i][j][e] = L[sw32(16 * i + 4 * g + e, 16 * j + cl)];

  // identity as a B-frag: I[4g+e][cl]
  f16x4 Ih;
  #pragma unroll
  for (int e = 0; e < 4; ++e)
    Ih[e] = (_Float16)(((4 * g + e) == cl) ? 1.0f : 0.0f);

  const f32x4 zero = {0.f, 0.f, 0.f, 0.f};

  #pragma unroll 1
  for (int it = 0; it < 13; ++it) {
    // f16 copy of the master (D-layout)
    f16x4 Zh[4][4];
    #pragma unroll
    for (int i = 0; i < 4; ++i)
      #pragma unroll
      for (int j = 0; j < 4; ++j) {
        #pragma unroll
        for (int e = 0; e < 4; ++e) Zh[i][j][e] = (_Float16)R[i][j][e];
      }

    // ---- G = Z^T Z ----  (Zh[k][i] as A == (Z_(k,i))^T ; Zh[k][j] as B == Z_(k,j))
    f32x4 G[4][4];
    #pragma unroll
    for (int i = 0; i < 4; ++i)
      #pragma unroll
      for (int j = 0; j < 4; ++j) {
        f32x4 a = MFMA16(Zh[0][i], Zh[0][j], zero);
        a = MFMA16(Zh[1][i], Zh[1][j], a);
        a = MFMA16(Zh[2][i], Zh[2][j], a);
        a = MFMA16(Zh[3][i], Zh[3][j], a);
        G[i][j] = a;
      }

    // ---- Th = f16(-0.5 G) in D-layout (as B-frag == tile (-0.5G)_(k,j)) ----
    f16x4 Th[4][4];
    #pragma unroll
    for (int i = 0; i < 4; ++i)
      #pragma unroll
      for (int j = 0; j < 4; ++j) {
        #pragma unroll
        for (int e = 0; e < 4; ++e) Th[i][j][e] = (_Float16)(-0.5f * G[i][j][e]);
      }

    // ---- identity-MFMA transpose: ZhT[i][k] == A-frag of Z_(i,k) ----
    f16x4 ZhT[4][4];
    #pragma unroll
    for (int i = 0; i < 4; ++i)
      #pragma unroll
      for (int k = 0; k < 4; ++k) {
        f32x4 t = MFMA16(Zh[i][k], Ih, zero);  // = (Z_(i,k))^T in D-layout
        #pragma unroll
        for (int e = 0; e < 4; ++e) ZhT[i][k][e] = (_Float16)t[e];  // exact (values are f16)
      }

    // ---- Z' = 1.5 Z + Z.(-0.5 G)  (output in D-layout == master layout) ----
    #pragma unroll
    for (int i = 0; i < 4; ++i)
      #pragma unroll
      for (int j = 0; j < 4; ++j) {
        f32x4 a = MFMA16(ZhT[i][0], Th[0][j], zero);
        a = MFMA16(ZhT[i][1], Th[1][j], a);
        a = MFMA16(ZhT[i][2], Th[2][j], a);
        a = MFMA16(ZhT[i][3], Th[3][j], a);
        R[i][j] = 1.5f * R[i][j] + a;
      }
  }

  // ---- un-transpose through LDS (scalar writes are 2-way/free with sw32) ----
  #pragma unroll
  for (int i = 0; i < 4; ++i)
    #pragma unroll
    for (int j = 0; j < 4; ++j)
      #pragma unroll
      for (int e = 0; e < 4; ++e)
        L[sw32(16 * i + 4 * g + e, 16 * j + cl)] = R[i][j][e];

  // ---- coalesced dwordx4 stores ----
  #pragma unroll
  for (int i = 0; i < 16; ++i) {
    const int row = 4 * i + g;
    f32x4 v = *(const f32x4*)(L + sw32(row, 4 * cl));
    *(f32x4*)(OUT + base + row * 64 + 4 * cl) = v;
  }
}

extern "C" void kernel_launch(void* const* d_in, const int* in_sizes, int n_in,
                              void* d_out, int out_size, void* d_ws, size_t ws_size,
                              hipStream_t stream) {
  (void)n_in; (void)d_ws; (void)ws_size; (void)out_size;
  const float* W = (const float*)d_in[0];
  float* out = (float*)d_out;
  const int batch = in_sizes[0] / 4096;  // 8192 matrices of 64x64
  BatchedBjorckOrthogonalization_45122926411979_kernel<<<dim3(batch), dim3(64), 0, stream>>>(W, out);
}